// Round 14
// baseline (250.843 us; speedup 1.0000x reference)
//
#include <hip/hip_runtime.h>
#include <hip/hip_bf16.h>

// out[b] = SCALE*query[b]@P[b] + row[b]
//   M  = Wc1^T + prev@Wc2^T            (Mt = M^T, fp32+bf16)
//   Tt[b] = NT(Mt, keyzT[b]) ; W2 = Wq^T@Wk ; u = Wq^T bk ; w3 = Wk^T bq
//   Pt[b] = NT(Tt[b], W2) + s1[b][d2]*u[d0]
//   row[b][d] = bc - 1e9*sm0 + SCALE*(w3@T[b] + (bq.bk)*s1)
// r14: g5's proven 1-barrier counted-prefetch structure applied to G3'/G4'
// (g34_pipe: 96x192, 8 waves, 3A+2B bufs, vmcnt(1) boundary) and launches
// collapsed 9 -> 5 (k_prep_all z-regions; k_sums in g34<3>; k_row in g34<4>).
// g5_pipe unchanged from r13 (winner). Rotation LDS swizzle (0 conflicts),
// XCD-bijective block swizzle, mask-constant path fp32.

typedef __attribute__((ext_vector_type(8))) short short8;
typedef __attribute__((ext_vector_type(4))) float f32x4;

#define SCALE 0.03608439182435161f   /* 1/sqrt(768) */

__device__ inline unsigned short f2bf(float x) {
  unsigned int u = __builtin_bit_cast(unsigned int, x);
  u = (u + 0x7fffu + ((u >> 16) & 1u)) >> 16;   // RNE
  return (unsigned short)u;
}
__device__ inline float bf2f(unsigned short h) {
  return __builtin_bit_cast(float, ((unsigned int)h) << 16);
}

// ---------------- fused prep: grid (12,12,34) ----------------
// z=0: WqT, z=1: WkT, z=2..9: keyzT[b] (transpose+cvt via LDS)
// z=10: prev cvt, z=11: Wc2 cvt, z=12..33: query cvt (tiled direct)
__global__ void k_prep_all(
    const float* __restrict__ Wq, const float* __restrict__ Wk,
    const float* __restrict__ key, const int* __restrict__ mask,
    const float* __restrict__ prev, const float* __restrict__ Wc,
    const float* __restrict__ query,
    unsigned short* __restrict__ WqT, unsigned short* __restrict__ WkT,
    unsigned short* __restrict__ keyzT, unsigned short* __restrict__ prev_bf,
    unsigned short* __restrict__ Wc2_bf, unsigned short* __restrict__ query_bf)
{
  __shared__ float t[64][65];
  const int z = blockIdx.z;
  const int tid = threadIdx.x;
  if (z < 10) {                       // transpose+cvt
    const float* src;
    unsigned short* dst;
    const int* mb = nullptr;
    if (z == 0) { src = Wq; dst = WqT; }
    else if (z == 1) { src = Wk; dst = WkT; }
    else {
      int b = z - 2;
      src = key + (long long)b * 589824;
      dst = keyzT + (long long)b * 589824;
      mb = mask + b * 768;
    }
    int bx = blockIdx.x * 64, by = blockIdx.y * 64;
    int tx = tid & 63, ty = tid >> 6;
    #pragma unroll
    for (int i = 0; i < 64; i += 4) {
      float v = src[(long long)(by + ty + i) * 768 + bx + tx];
      if (mb) v = mb[by + ty + i] ? v : 0.0f;
      t[ty + i][tx] = v;
    }
    __syncthreads();
    #pragma unroll
    for (int i = 0; i < 64; i += 4)
      dst[(long long)(bx + ty + i) * 768 + by + tx] = f2bf(t[tx][ty + i]);
    return;
  }
  // direct cvt regions: one 64x64 tile, thread = (row r, 16-col segment)
  const int r = tid >> 2, c0 = (tid & 3) * 16;
  const float* sr;
  unsigned short* dr;
  if (z == 10) {
    int row = blockIdx.y * 64 + r, col = blockIdx.x * 64 + c0;
    sr = prev + (long long)row * 768 + col;
    dr = prev_bf + (long long)row * 768 + col;
  } else if (z == 11) {
    int row = blockIdx.y * 64 + r, col = blockIdx.x * 64 + c0;
    sr = Wc + (long long)row * 1536 + 768 + col;
    dr = Wc2_bf + (long long)row * 768 + col;
  } else {
    int tz = (z - 12) * 144 + blockIdx.y * 12 + blockIdx.x;
    if (tz >= 3072) return;           // 8 b x 32 rowtiles x 12 coltiles
    int b = tz / 384, rmn = tz - b * 384;
    int rt = rmn / 12, ct = rmn - rt * 12;
    long long base = (long long)b * 1572864 + (long long)(rt * 64 + r) * 768 + ct * 64 + c0;
    sr = query + base;
    dr = query_bf + base;
  }
  #pragma unroll
  for (int q = 0; q < 4; ++q) {
    float4 v = *reinterpret_cast<const float4*>(sr + q * 4);
    *reinterpret_cast<ushort4*>(dr + q * 4) =
        make_ushort4(f2bf(v.x), f2bf(v.y), f2bf(v.z), f2bf(v.w));
  }
}

// ---------------- shared small-GEMM pieces ----------------
__device__ inline void xcd_swz(int& bx, int& by, int& bz) {
  const int gx = gridDim.x, gy = gridDim.y;
  const int nwg = gx * gy * (int)gridDim.z;
  int lin = blockIdx.x + gx * (blockIdx.y + gy * blockIdx.z);
  int qq = nwg >> 3, rr = nwg & 7, xcd = lin & 7, loc = lin >> 3;
  int swz = (xcd < rr ? xcd * (qq + 1) : rr * (qq + 1) + (xcd - rr) * qq) + loc;
  bz = swz / (gx * gy);
  int rem = swz - bz * gx * gy;
  by = rem / gx;
  bx = rem - by * gx;
}

__device__ inline void nt64_core(const unsigned short* Ab, int lda,
                                 const unsigned short* Bb, int ldb,
                                 int m0, int n0, int tid, f32x4 (&acc)[2][2],
                                 char* As, char* Bs) {
  const int w = tid >> 6, lane = tid & 63;
  const int wr = w >> 1, wc = w & 1;
  const int fr = lane & 15, fq = lane >> 4;
  for (int kt = 0; kt < 768; kt += 64) {
    __syncthreads();
    #pragma unroll
    for (int t = 0; t < 2; ++t) {
      int g = t * 256 + tid;
      int row = g >> 3, s = g & 7;
      int sg = (s - row) & 7;
      const unsigned short* ga = Ab + (long long)(m0 + row) * lda + kt + sg * 8;
      __builtin_amdgcn_global_load_lds(
          (const __attribute__((address_space(1))) void*)ga,
          (__attribute__((address_space(3))) void*)(As + g * 16), 16, 0, 0);
    }
    #pragma unroll
    for (int t = 0; t < 2; ++t) {
      int g = t * 256 + tid;
      int row = g >> 3, s = g & 7;
      int sg = (s - row) & 7;
      const unsigned short* gb = Bb + (long long)(n0 + row) * ldb + kt + sg * 8;
      __builtin_amdgcn_global_load_lds(
          (const __attribute__((address_space(1))) void*)gb,
          (__attribute__((address_space(3))) void*)(Bs + g * 16), 16, 0, 0);
    }
    __syncthreads();
    #pragma unroll
    for (int kk = 0; kk < 2; ++kk) {
      short8 af[2], bfr[2];
      #pragma unroll
      for (int i = 0; i < 2; ++i) {
        int r = wr * 32 + i * 16 + fr;
        af[i] = *reinterpret_cast<const short8*>(As + r * 128 + (((kk * 4 + fq) + r) & 7) * 16);
      }
      #pragma unroll
      for (int j = 0; j < 2; ++j) {
        int r = wc * 32 + j * 16 + fr;
        bfr[j] = *reinterpret_cast<const short8*>(Bs + r * 128 + (((kk * 4 + fq) + r) & 7) * 16);
      }
      #pragma unroll
      for (int i = 0; i < 2; ++i)
        #pragma unroll
        for (int j = 0; j < 2; ++j)
          acc[i][j] = __builtin_amdgcn_mfma_f32_16x16x32_bf16(af[i], bfr[j], acc[i][j], 0, 0, 0);
    }
  }
}

// fused G1 (z=0) + W2 (z=1)
__global__ __launch_bounds__(256) void gemm_g1w2(
    const unsigned short* __restrict__ Wc2_bf, const unsigned short* __restrict__ prev_bf,
    const unsigned short* __restrict__ WqT_bf, const unsigned short* __restrict__ WkT_bf,
    const float* __restrict__ Wc, float* __restrict__ Mt_f,
    unsigned short* __restrict__ Mt_bf, unsigned short* __restrict__ W2_bf)
{
  __shared__ __align__(16) char As[64 * 128];
  __shared__ __align__(16) char Bs[64 * 128];
  int bx, by, bz;
  xcd_swz(bx, by, bz);
  const int m0 = by * 64, n0 = bx * 64;
  const unsigned short* A = bz ? WqT_bf : Wc2_bf;
  const unsigned short* B = bz ? WkT_bf : prev_bf;
  const int tid = threadIdx.x;
  f32x4 acc[2][2] = {};
  nt64_core(A, 768, B, 768, m0, n0, tid, acc, As, Bs);

  const int w = tid >> 6, lane = tid & 63;
  const int wr = w >> 1, wc = w & 1;
  const int fr = lane & 15, fq = lane >> 4;
  #pragma unroll
  for (int i = 0; i < 2; ++i)
    #pragma unroll
    for (int j = 0; j < 2; ++j)
      #pragma unroll
      for (int r = 0; r < 4; ++r) {
        int row = m0 + wr * 32 + i * 16 + fq * 4 + r;
        int col = n0 + wc * 32 + j * 16 + fr;
        float v = acc[i][j][r];
        if (bz == 0) {
          v += Wc[(long long)row * 1536 + col];
          Mt_f[(long long)row * 768 + col] = v;
          Mt_bf[(long long)row * 768 + col] = f2bf(v);
        } else {
          W2_bf[(long long)row * 768 + col] = f2bf(v);
        }
      }
}

// ---------------- g34_pipe: 96x192 1-barrier counted GEMM + aux region --------
// MODE 3: C=Tt plain; z==8 region computes u/w3/s1/sm0 (k_sums)
// MODE 4: C=Pt + s1[m]*u[n]; z==8 region computes rowv (k_row)
template <int MODE>
__global__ __launch_bounds__(512, 1) void g34_pipe(
    const unsigned short* __restrict__ A, long long aStr,
    const unsigned short* __restrict__ B, long long bStr,
    unsigned short* __restrict__ C,
    const float* __restrict__ s1, const float* __restrict__ uv,
    const unsigned short* __restrict__ WqT, const unsigned short* __restrict__ WkT,
    const float* __restrict__ bk, const float* __restrict__ bq,
    const float* __restrict__ Mt_f, const int* __restrict__ mask,
    const unsigned short* __restrict__ Tt, const float* __restrict__ w3,
    const float* __restrict__ sm0, const float* __restrict__ bc,
    float* __restrict__ o_u, float* __restrict__ o_w3,
    float* __restrict__ o_s1, float* __restrict__ o_sm0, float* __restrict__ o_row)
{
  __shared__ __align__(16) char As[3][96 * 128];    // 3 x 12 KB
  __shared__ __align__(16) char Bs[2][192 * 128];   // 2 x 24 KB

  // bijective swizzle, nwg = 4*8*9 = 288 (divisible by 8)
  int lin = blockIdx.x + 4 * (blockIdx.y + 8 * blockIdx.z);
  int swz = (lin & 7) * 36 + (lin >> 3);
  int bz = swz >> 5;
  int rem = swz & 31;
  int by = rem >> 2, bx = rem & 3;

  const int tid = threadIdx.x;
  const int wv = tid >> 6, lane = tid & 63;

  if (bz == 8) {                       // aux region: 32 blocks x 8 waves
    int gw0 = (swz - 256) * 8 + wv;
    if constexpr (MODE == 3) {         // sums: 1536 scalar units + 6144 colsum units
      for (int unit = gw0; unit < 7680; unit += 256) {
        if (unit < 1536) {
          const unsigned short* wrow = (unit < 768) ? (WqT + (long long)unit * 768)
                                                    : (WkT + (long long)(unit - 768) * 768);
          const float* vec = (unit < 768) ? bk : bq;
          float s = 0.f;
          for (int j = lane; j < 768; j += 64) s += bf2f(wrow[j]) * vec[j];
          #pragma unroll
          for (int off = 32; off > 0; off >>= 1) s += __shfl_down(s, off, 64);
          if (lane == 0) { if (unit < 768) o_u[unit] = s; else o_w3[unit - 768] = s; }
        } else {
          int g2 = unit - 1536;
          int b = g2 / 768, d2 = g2 - b * 768;
          const int* mb = mask + b * 768;
          const float* mrow = Mt_f + (long long)d2 * 768;
          float a1 = 0.f, a0 = 0.f;
          for (int k = lane; k < 768; k += 64) {
            float v = mrow[k];
            if (mb[k]) a1 += v; else a0 += v;
          }
          #pragma unroll
          for (int off = 32; off > 0; off >>= 1) {
            a1 += __shfl_down(a1, off, 64);
            a0 += __shfl_down(a0, off, 64);
          }
          if (lane == 0) { o_s1[g2] = a1; o_sm0[g2] = a0; }
        }
      }
    } else {                           // row: 6144 units
      for (int unit = gw0; unit < 6144; unit += 256) {
        int b = unit / 768, d2 = unit - b * 768;
        const unsigned short* trow = Tt + ((long long)b * 768 + d2) * 768;
        float st = 0.f, sbb = 0.f;
        for (int j = lane; j < 768; j += 64) {
          st += bf2f(trow[j]) * w3[j];
          sbb += bq[j] * bk[j];
        }
        #pragma unroll
        for (int off = 32; off > 0; off >>= 1) {
          st += __shfl_down(st, off, 64);
          sbb += __shfl_down(sbb, off, 64);
        }
        if (lane == 0)
          o_row[unit] = bc[d2] - 1e9f * sm0[unit] + SCALE * (st + sbb * s1[unit]);
      }
    }
    return;
  }

  const int b = bz;
  const int m0 = by * 96, n0 = bx * 192;
  const unsigned short* Ab = A + (long long)b * aStr;
  const unsigned short* Bb = B + (long long)b * bStr;
  const int wr = wv >> 2, wn = wv & 3;    // 2 M-waves x 4 N-waves
  const int fr = lane & 15, fq = lane >> 4;

  f32x4 acc[3][3] = {};

  auto stageA = [&](int buf, int kt) {    // 96 rows x 8 granules = 768 (1.5 iters)
    #pragma unroll
    for (int s = 0; s < 2; ++s) {
      int g = s * 512 + tid;
      if (g < 768) {                      // wave-uniform: iter1 only waves 0-3
        int row = g >> 3, slot = g & 7;
        int sg = (slot - row) & 7;
        const unsigned short* ga = Ab + (long long)(m0 + row) * 768 + kt + sg * 8;
        __builtin_amdgcn_global_load_lds(
            (const __attribute__((address_space(1))) void*)ga,
            (__attribute__((address_space(3))) void*)(&As[buf][0] + g * 16), 16, 0, 0);
      }
    }
  };
  auto stageB = [&](int buf, int kt) {    // 192 rows x 8 = 1536 granules (3 iters)
    #pragma unroll
    for (int s = 0; s < 3; ++s) {
      int g = s * 512 + tid;
      int row = g >> 3, slot = g & 7;
      int sg = (slot - row) & 7;
      const unsigned short* gb = Bb + (long long)(n0 + row) * 768 + kt + sg * 8;
      __builtin_amdgcn_global_load_lds(
          (const __attribute__((address_space(1))) void*)gb,
          (__attribute__((address_space(3))) void*)(&Bs[buf][0] + g * 16), 16, 0, 0);
    }
  };

  // prologue: A(0), B(0), deep-prefetch A(1); wait all but A(1)
  stageA(0, 0);
  stageB(0, 0);
  stageA(1, 64);
  asm volatile("s_waitcnt vmcnt(1)" ::: "memory");
  __builtin_amdgcn_s_barrier();

  for (int t = 0; t < 12; ++t) {
    const char* as = &As[t % 3][0];
    const char* bs = &Bs[t & 1][0];

    if (t < 11) stageB((t + 1) & 1, (t + 1) * 64);
    if (t < 10) stageA((t + 2) % 3, (t + 2) * 64);

    #pragma unroll
    for (int kk = 0; kk < 2; ++kk) {
      short8 a[3], bb[3];
      #pragma unroll
      for (int i = 0; i < 3; ++i) {
        int r = wr * 48 + i * 16 + fr;
        a[i] = *reinterpret_cast<const short8*>(as + r * 128 + (((kk * 4 + fq) + r) & 7) * 16);
      }
      #pragma unroll
      for (int j = 0; j < 3; ++j) {
        int r = wn * 48 + j * 16 + fr;
        bb[j] = *reinterpret_cast<const short8*>(bs + r * 128 + (((kk * 4 + fq) + r) & 7) * 16);
      }
      __builtin_amdgcn_s_setprio(1);
      #pragma unroll
      for (int i = 0; i < 3; ++i)
        #pragma unroll
        for (int j = 0; j < 3; ++j)
          acc[i][j] = __builtin_amdgcn_mfma_f32_16x16x32_bf16(a[i], bb[j], acc[i][j], 0, 0, 0);
      __builtin_amdgcn_s_setprio(0);
    }

    // counted boundary: newest in flight = A(t+2) (2 instrs waves 0-3, 1 waves 4-7)
    if (t < 10)       asm volatile("s_waitcnt vmcnt(1)" ::: "memory");
    else if (t == 10) asm volatile("s_waitcnt vmcnt(0)" ::: "memory");
    __builtin_amdgcn_s_barrier();
  }

  #pragma unroll
  for (int i = 0; i < 3; ++i)
    #pragma unroll
    for (int j = 0; j < 3; ++j)
      #pragma unroll
      for (int r = 0; r < 4; ++r) {
        int row = m0 + wr * 48 + i * 16 + fq * 4 + r;
        int col = n0 + wn * 48 + j * 16 + fr;
        float v = acc[i][j][r];
        if constexpr (MODE == 4) v += s1[b * 768 + row] * uv[col];
        C[(long long)b * 589824 + (long long)row * 768 + col] = f2bf(v);
      }
}

// ---------------- G5: 1 barrier per K-tile, counted vmcnt, 3 A-bufs (r13) ------
__global__ __launch_bounds__(512, 1) void g5_pipe(
    const unsigned short* __restrict__ A,   // query_bf [8][2048][768]
    const unsigned short* __restrict__ B,   // Pt [8][768][768]
    float* __restrict__ C, const float* __restrict__ rowv)
{
  __shared__ __align__(16) char As[3][256 * 128];   // 3 x 32 KB
  __shared__ __align__(16) char Bs[2][192 * 128];   // 2 x 24 KB

  int lin = blockIdx.x + 4 * (blockIdx.y + 8 * blockIdx.z);
  int swz = (lin & 7) * 32 + (lin >> 3);
  int bz = swz >> 5;
  int rem = swz & 31;
  int by = rem >> 2, bx = rem & 3;

  const int b = bz;
  const int m0 = by * 256, n0 = bx * 192;
  const unsigned short* Ab = A + (long long)b * 1572864;
  const unsigned short* Bb = B + (long long)b * 589824;

  const int tid = threadIdx.x;
  const int w = tid >> 6, lane = tid & 63;
  const int wr = w >> 2, wn = w & 3;
  const int fr = lane & 15, fq = lane >> 4;

  f32x4 acc[8][3] = {};

  auto stageA = [&](int buf, int kt) {
    #pragma unroll
    for (int s = 0; s < 4; ++s) {
      int g = s * 512 + tid;
      int row = g >> 3, slot = g & 7;
      int sg = (slot - row) & 7;
      const unsigned short* ga = Ab + (long long)(m0 + row) * 768 + kt + sg * 8;
      __builtin_amdgcn_global_load_lds(
          (const __attribute__((address_space(1))) void*)ga,
          (__attribute__((address_space(3))) void*)(&As[buf][0] + g * 16), 16, 0, 0);
    }
  };
  auto stageB = [&](int buf, int kt) {
    #pragma unroll
    for (int s = 0; s < 3; ++s) {
      int g = s * 512 + tid;
      int row = g >> 3, slot = g & 7;
      int sg = (slot - row) & 7;
      const unsigned short* gb = Bb + (long long)(n0 + row) * 768 + kt + sg * 8;
      __builtin_amdgcn_global_load_lds(
          (const __attribute__((address_space(1))) void*)gb,
          (__attribute__((address_space(3))) void*)(&Bs[buf][0] + g * 16), 16, 0, 0);
    }
  };

  stageA(0, 0);
  stageB(0, 0);
  stageA(1, 64);
  asm volatile("s_waitcnt vmcnt(4)" ::: "memory");
  __builtin_amdgcn_s_barrier();

  for (int t = 0; t < 12; ++t) {
    const char* as = &As[t % 3][0];
    const char* bs = &Bs[t & 1][0];

    if (t < 11) stageB((t + 1) & 1, (t + 1) * 64);
    if (t < 10) stageA((t + 2) % 3, (t + 2) * 64);

    #pragma unroll
    for (int kk = 0; kk < 2; ++kk) {
      short8 a[8], bb[3];
      #pragma unroll
      for (int i = 0; i < 8; ++i) {
        int r = wr * 128 + i * 16 + fr;
        a[i] = *reinterpret_cast<const short8*>(as + r * 128 + (((kk * 4 + fq) + r) & 7) * 16);
      }
      #pragma unroll
      for (int j = 0; j < 3; ++j) {
        int r = wn * 48 + j * 16 + fr;
        bb[j] = *reinterpret_cast<const short8*>(bs + r * 128 + (((kk * 4 + fq) + r) & 7) * 16);
      }
      __builtin_amdgcn_s_setprio(1);
      #pragma unroll
      for (int i = 0; i < 8; ++i)
        #pragma unroll
        for (int j = 0; j < 3; ++j)
          acc[i][j] = __builtin_amdgcn_mfma_f32_16x16x32_bf16(a[i], bb[j], acc[i][j], 0, 0, 0);
      __builtin_amdgcn_s_setprio(0);
    }

    if (t < 10)       asm volatile("s_waitcnt vmcnt(4)" ::: "memory");
    else if (t == 10) asm volatile("s_waitcnt vmcnt(0)" ::: "memory");
    __builtin_amdgcn_s_barrier();
  }

  const long long ob = (long long)b * 1572864;
  #pragma unroll
  for (int i = 0; i < 8; ++i)
    #pragma unroll
    for (int j = 0; j < 3; ++j)
      #pragma unroll
      for (int r = 0; r < 4; ++r) {
        int row = m0 + wr * 128 + i * 16 + fq * 4 + r;
        int col = n0 + wn * 48 + j * 16 + fr;
        C[ob + (long long)row * 768 + col] = acc[i][j][r] * SCALE + rowv[b * 768 + col];
      }
}

extern "C" void kernel_launch(void* const* d_in, const int* in_sizes, int n_in,
                              void* d_out, int out_size, void* d_ws, size_t ws_size,
                              hipStream_t stream)
{
  const float* query = (const float*)d_in[0];
  const float* key   = (const float*)d_in[1];
  const float* prev  = (const float*)d_in[3];
  const int*   mask  = (const int*)d_in[4];
  const float* Wq    = (const float*)d_in[5];
  const float* bq    = (const float*)d_in[6];
  const float* Wk    = (const float*)d_in[7];
  const float* bk    = (const float*)d_in[8];
  const float* Wc    = (const float*)d_in[11];
  const float* bc    = (const float*)d_in[12];
  float* out = (float*)d_out;

  char* p = (char*)d_ws;
  size_t off = 0;
  auto alloc = [&](size_t bytes) {
    char* r = p + off;
    off += (bytes + 255) & ~(size_t)255;
    return r;
  };
  unsigned short* query_bf = (unsigned short*)alloc(12582912ull * 2);
  unsigned short* keyzT_bf = (unsigned short*)alloc(4718592ull * 2);
  unsigned short* WqT_bf   = (unsigned short*)alloc(589824ull * 2);
  unsigned short* WkT_bf   = (unsigned short*)alloc(589824ull * 2);
  unsigned short* prev_bf  = (unsigned short*)alloc(589824ull * 2);
  unsigned short* Wc2_bf   = (unsigned short*)alloc(589824ull * 2);
  float*          Mt_f     = (float*)alloc(589824ull * 4);
  unsigned short* Mt_bf    = (unsigned short*)alloc(589824ull * 2);
  unsigned short* W2_bf    = (unsigned short*)alloc(589824ull * 2);
  unsigned short* Tt_bf    = (unsigned short*)alloc(4718592ull * 2);
  unsigned short* Pt_bf    = (unsigned short*)alloc(4718592ull * 2);
  float*          s1f      = (float*)alloc(6144ull * 4);
  float*          sm0f     = (float*)alloc(6144ull * 4);
  float*          uv       = (float*)alloc(768ull * 4);
  float*          w3v      = (float*)alloc(768ull * 4);
  float*          rowv     = (float*)alloc(6144ull * 4);
  (void)ws_size; (void)in_sizes; (void)n_in; (void)out_size;

  // 1) all conversions/transposes
  k_prep_all<<<dim3(12, 12, 34), dim3(256), 0, stream>>>(
      Wq, Wk, key, mask, prev, Wc, query,
      WqT_bf, WkT_bf, keyzT_bf, prev_bf, Wc2_bf, query_bf);
  // 2) G1 + W2
  gemm_g1w2<<<dim3(12, 12, 2), dim3(256), 0, stream>>>(
      Wc2_bf, prev_bf, WqT_bf, WkT_bf, Wc, Mt_f, Mt_bf, W2_bf);
  // 3) G3' (Tt) + sums region
  g34_pipe<3><<<dim3(4, 8, 9), dim3(512), 0, stream>>>(
      Mt_bf, 0ll, keyzT_bf, 589824ll, Tt_bf,
      (const float*)nullptr, (const float*)nullptr,
      WqT_bf, WkT_bf, bk, bq, Mt_f, mask,
      (const unsigned short*)nullptr, (const float*)nullptr,
      (const float*)nullptr, (const float*)nullptr,
      uv, w3v, s1f, sm0f, (float*)nullptr);
  // 4) G4' (Pt + rank-1) + row region
  g34_pipe<4><<<dim3(4, 8, 9), dim3(512), 0, stream>>>(
      Tt_bf, 589824ll, W2_bf, 0ll, Pt_bf,
      s1f, uv,
      (const unsigned short*)nullptr, (const unsigned short*)nullptr, bk, bq,
      (const float*)nullptr, (const int*)nullptr,
      Tt_bf, w3v, sm0f, bc,
      (float*)nullptr, (float*)nullptr, (float*)nullptr, (float*)nullptr, rowv);
  // 5) G5
  g5_pipe<<<dim3(4, 8, 8), dim3(512), 0, stream>>>(query_bf, Pt_bf, out, rowv);
}

// Round 15
// 107.748 us; speedup vs baseline: 2.3280x; 2.3280x over previous
//
#include <hip/hip_runtime.h>
#include <hip/hip_bf16.h>

// out[b] = SCALE*query[b]@P[b] + row[b]
//   M  = Wc1^T + prev@Wc2^T            (Mt = M^T, fp32+bf16)
//   Tt[b] = NT(Mt, keyzT[b]) ; W2 = Wq^T@Wk ; u = Wq^T bk ; w3 = Wk^T bq
//   Pt[b] = NT(Tt[b], W2) + s1[b][d2]*u[d0]
//   row[b][d] = bc - 1e9*sm0 + SCALE*(w3@T[b] + (bq.bk)*s1)
// r15: r14's aux-region fusion REVERTED (it ran latency-bound reductions at
// 256 waves chip-wide -> 100us; occupancy counter 5.4% was the tell).
// g34_pipe is now pure GEMM at grid 256 = 1/CU; k_sums/k_row back as wide
// launches (r13 form). k_prep_all, gemm_g1w2, g5_pipe unchanged (proven).
// All GEMMs: 1-barrier/K-tile counted-vmcnt pipeline, rotation LDS swizzle
// (0 conflicts measured), XCD-bijective swizzle, mask-constant path fp32.

typedef __attribute__((ext_vector_type(8))) short short8;
typedef __attribute__((ext_vector_type(4))) float f32x4;

#define SCALE 0.03608439182435161f   /* 1/sqrt(768) */

__device__ inline unsigned short f2bf(float x) {
  unsigned int u = __builtin_bit_cast(unsigned int, x);
  u = (u + 0x7fffu + ((u >> 16) & 1u)) >> 16;   // RNE
  return (unsigned short)u;
}
__device__ inline float bf2f(unsigned short h) {
  return __builtin_bit_cast(float, ((unsigned int)h) << 16);
}

// ---------------- fused prep: grid (12,12,34) ----------------
// z=0: WqT, z=1: WkT, z=2..9: keyzT[b] (transpose+cvt via LDS)
// z=10: prev cvt, z=11: Wc2 cvt, z=12..33: query cvt (tiled direct)
__global__ void k_prep_all(
    const float* __restrict__ Wq, const float* __restrict__ Wk,
    const float* __restrict__ key, const int* __restrict__ mask,
    const float* __restrict__ prev, const float* __restrict__ Wc,
    const float* __restrict__ query,
    unsigned short* __restrict__ WqT, unsigned short* __restrict__ WkT,
    unsigned short* __restrict__ keyzT, unsigned short* __restrict__ prev_bf,
    unsigned short* __restrict__ Wc2_bf, unsigned short* __restrict__ query_bf)
{
  __shared__ float t[64][65];
  const int z = blockIdx.z;
  const int tid = threadIdx.x;
  if (z < 10) {                       // transpose+cvt
    const float* src;
    unsigned short* dst;
    const int* mb = nullptr;
    if (z == 0) { src = Wq; dst = WqT; }
    else if (z == 1) { src = Wk; dst = WkT; }
    else {
      int b = z - 2;
      src = key + (long long)b * 589824;
      dst = keyzT + (long long)b * 589824;
      mb = mask + b * 768;
    }
    int bx = blockIdx.x * 64, by = blockIdx.y * 64;
    int tx = tid & 63, ty = tid >> 6;
    #pragma unroll
    for (int i = 0; i < 64; i += 4) {
      float v = src[(long long)(by + ty + i) * 768 + bx + tx];
      if (mb) v = mb[by + ty + i] ? v : 0.0f;
      t[ty + i][tx] = v;
    }
    __syncthreads();
    #pragma unroll
    for (int i = 0; i < 64; i += 4)
      dst[(long long)(bx + ty + i) * 768 + by + tx] = f2bf(t[tx][ty + i]);
    return;
  }
  // direct cvt regions: one 64x64 tile, thread = (row r, 16-col segment)
  const int r = tid >> 2, c0 = (tid & 3) * 16;
  const float* sr;
  unsigned short* dr;
  if (z == 10) {
    int row = blockIdx.y * 64 + r, col = blockIdx.x * 64 + c0;
    sr = prev + (long long)row * 768 + col;
    dr = prev_bf + (long long)row * 768 + col;
  } else if (z == 11) {
    int row = blockIdx.y * 64 + r, col = blockIdx.x * 64 + c0;
    sr = Wc + (long long)row * 1536 + 768 + col;
    dr = Wc2_bf + (long long)row * 768 + col;
  } else {
    int tz = (z - 12) * 144 + blockIdx.y * 12 + blockIdx.x;
    if (tz >= 3072) return;           // 8 b x 32 rowtiles x 12 coltiles
    int b = tz / 384, rmn = tz - b * 384;
    int rt = rmn / 12, ct = rmn - rt * 12;
    long long base = (long long)b * 1572864 + (long long)(rt * 64 + r) * 768 + ct * 64 + c0;
    sr = query + base;
    dr = query_bf + base;
  }
  #pragma unroll
  for (int q = 0; q < 4; ++q) {
    float4 v = *reinterpret_cast<const float4*>(sr + q * 4);
    *reinterpret_cast<ushort4*>(dr + q * 4) =
        make_ushort4(f2bf(v.x), f2bf(v.y), f2bf(v.z), f2bf(v.w));
  }
}

// fused reductions (wide launch): gw<1536 -> u/w3; gw>=1536 -> s1/sm0
__global__ void k_sums(const unsigned short* __restrict__ WqT,
                       const unsigned short* __restrict__ WkT,
                       const float* __restrict__ bk, const float* __restrict__ bq,
                       const float* __restrict__ Mt, const int* __restrict__ mask,
                       float* __restrict__ u, float* __restrict__ w3,
                       float* __restrict__ s1, float* __restrict__ sm0) {
  int gw = blockIdx.x * 4 + (threadIdx.x >> 6);
  int lane = threadIdx.x & 63;
  if (gw < 1536) {
    const unsigned short* wrow = (gw < 768) ? (WqT + (long long)gw * 768)
                                            : (WkT + (long long)(gw - 768) * 768);
    const float* vec = (gw < 768) ? bk : bq;
    float s = 0.f;
    for (int j = lane; j < 768; j += 64) s += bf2f(wrow[j]) * vec[j];
    #pragma unroll
    for (int off = 32; off > 0; off >>= 1) s += __shfl_down(s, off, 64);
    if (lane == 0) { if (gw < 768) u[gw] = s; else w3[gw - 768] = s; }
  } else {
    int g2 = gw - 1536;
    int b = g2 / 768, d2 = g2 - b * 768;
    if (b >= 8) return;
    const int* mb = mask + b * 768;
    const float* mrow = Mt + (long long)d2 * 768;
    float a1 = 0.f, a0 = 0.f;
    for (int k = lane; k < 768; k += 64) {
      float v = mrow[k];
      if (mb[k]) a1 += v; else a0 += v;
    }
    #pragma unroll
    for (int off = 32; off > 0; off >>= 1) {
      a1 += __shfl_down(a1, off, 64);
      a0 += __shfl_down(a0, off, 64);
    }
    if (lane == 0) { s1[g2] = a1; sm0[g2] = a0; }
  }
}

// row[b][d2] = bc - 1e9*sm0 + SCALE*(Tt[b][d2]·w3 + (bq·bk)*s1)  (wide launch)
__global__ void k_row(const unsigned short* __restrict__ Tt, const float* __restrict__ w3,
                      const float* __restrict__ s1, const float* __restrict__ sm0,
                      const float* __restrict__ bq, const float* __restrict__ bk,
                      const float* __restrict__ bc, float* __restrict__ row) {
  int gw = blockIdx.x * 4 + (threadIdx.x >> 6);
  int lane = threadIdx.x & 63;
  int b = gw / 768, d2 = gw - b * 768;
  if (b >= 8) return;
  const unsigned short* trow = Tt + ((long long)b * 768 + d2) * 768;
  float st = 0.f, sbb = 0.f;
  for (int j = lane; j < 768; j += 64) {
    st += bf2f(trow[j]) * w3[j];
    sbb += bq[j] * bk[j];
  }
  #pragma unroll
  for (int off = 32; off > 0; off >>= 1) {
    st += __shfl_down(st, off, 64);
    sbb += __shfl_down(sbb, off, 64);
  }
  if (lane == 0)
    row[gw] = bc[d2] - 1e9f * sm0[gw] + SCALE * (st + sbb * s1[gw]);
}

// ---------------- shared small-GEMM pieces ----------------
__device__ inline void xcd_swz(int& bx, int& by, int& bz) {
  const int gx = gridDim.x, gy = gridDim.y;
  const int nwg = gx * gy * (int)gridDim.z;
  int lin = blockIdx.x + gx * (blockIdx.y + gy * blockIdx.z);
  int qq = nwg >> 3, rr = nwg & 7, xcd = lin & 7, loc = lin >> 3;
  int swz = (xcd < rr ? xcd * (qq + 1) : rr * (qq + 1) + (xcd - rr) * qq) + loc;
  bz = swz / (gx * gy);
  int rem = swz - bz * gx * gy;
  by = rem / gx;
  bx = rem - by * gx;
}

__device__ inline void nt64_core(const unsigned short* Ab, int lda,
                                 const unsigned short* Bb, int ldb,
                                 int m0, int n0, int tid, f32x4 (&acc)[2][2],
                                 char* As, char* Bs) {
  const int w = tid >> 6, lane = tid & 63;
  const int wr = w >> 1, wc = w & 1;
  const int fr = lane & 15, fq = lane >> 4;
  for (int kt = 0; kt < 768; kt += 64) {
    __syncthreads();
    #pragma unroll
    for (int t = 0; t < 2; ++t) {
      int g = t * 256 + tid;
      int row = g >> 3, s = g & 7;
      int sg = (s - row) & 7;
      const unsigned short* ga = Ab + (long long)(m0 + row) * lda + kt + sg * 8;
      __builtin_amdgcn_global_load_lds(
          (const __attribute__((address_space(1))) void*)ga,
          (__attribute__((address_space(3))) void*)(As + g * 16), 16, 0, 0);
    }
    #pragma unroll
    for (int t = 0; t < 2; ++t) {
      int g = t * 256 + tid;
      int row = g >> 3, s = g & 7;
      int sg = (s - row) & 7;
      const unsigned short* gb = Bb + (long long)(n0 + row) * ldb + kt + sg * 8;
      __builtin_amdgcn_global_load_lds(
          (const __attribute__((address_space(1))) void*)gb,
          (__attribute__((address_space(3))) void*)(Bs + g * 16), 16, 0, 0);
    }
    __syncthreads();
    #pragma unroll
    for (int kk = 0; kk < 2; ++kk) {
      short8 af[2], bfr[2];
      #pragma unroll
      for (int i = 0; i < 2; ++i) {
        int r = wr * 32 + i * 16 + fr;
        af[i] = *reinterpret_cast<const short8*>(As + r * 128 + (((kk * 4 + fq) + r) & 7) * 16);
      }
      #pragma unroll
      for (int j = 0; j < 2; ++j) {
        int r = wc * 32 + j * 16 + fr;
        bfr[j] = *reinterpret_cast<const short8*>(Bs + r * 128 + (((kk * 4 + fq) + r) & 7) * 16);
      }
      #pragma unroll
      for (int i = 0; i < 2; ++i)
        #pragma unroll
        for (int j = 0; j < 2; ++j)
          acc[i][j] = __builtin_amdgcn_mfma_f32_16x16x32_bf16(af[i], bfr[j], acc[i][j], 0, 0, 0);
    }
  }
}

// fused G1 (z=0) + W2 (z=1)
__global__ __launch_bounds__(256) void gemm_g1w2(
    const unsigned short* __restrict__ Wc2_bf, const unsigned short* __restrict__ prev_bf,
    const unsigned short* __restrict__ WqT_bf, const unsigned short* __restrict__ WkT_bf,
    const float* __restrict__ Wc, float* __restrict__ Mt_f,
    unsigned short* __restrict__ Mt_bf, unsigned short* __restrict__ W2_bf)
{
  __shared__ __align__(16) char As[64 * 128];
  __shared__ __align__(16) char Bs[64 * 128];
  int bx, by, bz;
  xcd_swz(bx, by, bz);
  const int m0 = by * 64, n0 = bx * 64;
  const unsigned short* A = bz ? WqT_bf : Wc2_bf;
  const unsigned short* B = bz ? WkT_bf : prev_bf;
  const int tid = threadIdx.x;
  f32x4 acc[2][2] = {};
  nt64_core(A, 768, B, 768, m0, n0, tid, acc, As, Bs);

  const int w = tid >> 6, lane = tid & 63;
  const int wr = w >> 1, wc = w & 1;
  const int fr = lane & 15, fq = lane >> 4;
  #pragma unroll
  for (int i = 0; i < 2; ++i)
    #pragma unroll
    for (int j = 0; j < 2; ++j)
      #pragma unroll
      for (int r = 0; r < 4; ++r) {
        int row = m0 + wr * 32 + i * 16 + fq * 4 + r;
        int col = n0 + wc * 32 + j * 16 + fr;
        float v = acc[i][j][r];
        if (bz == 0) {
          v += Wc[(long long)row * 1536 + col];
          Mt_f[(long long)row * 768 + col] = v;
          Mt_bf[(long long)row * 768 + col] = f2bf(v);
        } else {
          W2_bf[(long long)row * 768 + col] = f2bf(v);
        }
      }
}

// ---------------- g34_pipe: 96x192 1-barrier counted GEMM (pure, 256 blocks) --
// MODE 3: C=Tt plain; MODE 4: C=Pt + s1[m]*u[n]
template <int MODE>
__global__ __launch_bounds__(512, 1) void g34_pipe(
    const unsigned short* __restrict__ A, long long aStr,
    const unsigned short* __restrict__ B, long long bStr,
    unsigned short* __restrict__ C,
    const float* __restrict__ s1, const float* __restrict__ uv)
{
  __shared__ __align__(16) char As[3][96 * 128];    // 3 x 12 KB
  __shared__ __align__(16) char Bs[2][192 * 128];   // 2 x 24 KB

  // grid 4x8x8 = 256, divisible by 8 -> simple chunked swizzle
  int lin = blockIdx.x + 4 * (blockIdx.y + 8 * blockIdx.z);
  int swz = (lin & 7) * 32 + (lin >> 3);
  int bz = swz >> 5;
  int rem = swz & 31;
  int by = rem >> 2, bx = rem & 3;

  const int tid = threadIdx.x;
  const int wv = tid >> 6, lane = tid & 63;
  const int b = bz;
  const int m0 = by * 96, n0 = bx * 192;
  const unsigned short* Ab = A + (long long)b * aStr;
  const unsigned short* Bb = B + (long long)b * bStr;
  const int wr = wv >> 2, wn = wv & 3;    // 2 M-waves x 4 N-waves
  const int fr = lane & 15, fq = lane >> 4;

  f32x4 acc[3][3] = {};

  auto stageA = [&](int buf, int kt) {    // 96 rows x 8 granules = 768 (1.5 iters)
    #pragma unroll
    for (int s = 0; s < 2; ++s) {
      int g = s * 512 + tid;
      if (g < 768) {                      // wave-uniform split (waves 0-3 only, s=1)
        int row = g >> 3, slot = g & 7;
        int sg = (slot - row) & 7;
        const unsigned short* ga = Ab + (long long)(m0 + row) * 768 + kt + sg * 8;
        __builtin_amdgcn_global_load_lds(
            (const __attribute__((address_space(1))) void*)ga,
            (__attribute__((address_space(3))) void*)(&As[buf][0] + g * 16), 16, 0, 0);
      }
    }
  };
  auto stageB = [&](int buf, int kt) {    // 192 rows x 8 = 1536 granules (3 iters)
    #pragma unroll
    for (int s = 0; s < 3; ++s) {
      int g = s * 512 + tid;
      int row = g >> 3, slot = g & 7;
      int sg = (slot - row) & 7;
      const unsigned short* gb = Bb + (long long)(n0 + row) * 768 + kt + sg * 8;
      __builtin_amdgcn_global_load_lds(
          (const __attribute__((address_space(1))) void*)gb,
          (__attribute__((address_space(3))) void*)(&Bs[buf][0] + g * 16), 16, 0, 0);
    }
  };

  // prologue: A(0), B(0), deep-prefetch A(1); wait all but A(1)
  stageA(0, 0);
  stageB(0, 0);
  stageA(1, 64);
  asm volatile("s_waitcnt vmcnt(1)" ::: "memory");
  __builtin_amdgcn_s_barrier();

  for (int t = 0; t < 12; ++t) {
    const char* as = &As[t % 3][0];
    const char* bs = &Bs[t & 1][0];

    if (t < 11) stageB((t + 1) & 1, (t + 1) * 64);
    if (t < 10) stageA((t + 2) % 3, (t + 2) * 64);

    #pragma unroll
    for (int kk = 0; kk < 2; ++kk) {
      short8 a[3], bb[3];
      #pragma unroll
      for (int i = 0; i < 3; ++i) {
        int r = wr * 48 + i * 16 + fr;
        a[i] = *reinterpret_cast<const short8*>(as + r * 128 + (((kk * 4 + fq) + r) & 7) * 16);
      }
      #pragma unroll
      for (int j = 0; j < 3; ++j) {
        int r = wn * 48 + j * 16 + fr;
        bb[j] = *reinterpret_cast<const short8*>(bs + r * 128 + (((kk * 4 + fq) + r) & 7) * 16);
      }
      __builtin_amdgcn_s_setprio(1);
      #pragma unroll
      for (int i = 0; i < 3; ++i)
        #pragma unroll
        for (int j = 0; j < 3; ++j)
          acc[i][j] = __builtin_amdgcn_mfma_f32_16x16x32_bf16(a[i], bb[j], acc[i][j], 0, 0, 0);
      __builtin_amdgcn_s_setprio(0);
    }

    // counted boundary (newest in flight = A(t+2))
    if (t < 10)       asm volatile("s_waitcnt vmcnt(1)" ::: "memory");
    else if (t == 10) asm volatile("s_waitcnt vmcnt(0)" ::: "memory");
    __builtin_amdgcn_s_barrier();
  }

  #pragma unroll
  for (int i = 0; i < 3; ++i)
    #pragma unroll
    for (int j = 0; j < 3; ++j)
      #pragma unroll
      for (int r = 0; r < 4; ++r) {
        int row = m0 + wr * 48 + i * 16 + fq * 4 + r;
        int col = n0 + wn * 48 + j * 16 + fr;
        float v = acc[i][j][r];
        if constexpr (MODE == 4) v += s1[b * 768 + row] * uv[col];
        C[(long long)b * 589824 + (long long)row * 768 + col] = f2bf(v);
      }
}

// ---------------- G5: 1 barrier per K-tile, counted vmcnt, 3 A-bufs (r13) ------
__global__ __launch_bounds__(512, 1) void g5_pipe(
    const unsigned short* __restrict__ A,   // query_bf [8][2048][768]
    const unsigned short* __restrict__ B,   // Pt [8][768][768]
    float* __restrict__ C, const float* __restrict__ rowv)
{
  __shared__ __align__(16) char As[3][256 * 128];   // 3 x 32 KB
  __shared__ __align__(16) char Bs[2][192 * 128];   // 2 x 24 KB

  int lin = blockIdx.x + 4 * (blockIdx.y + 8 * blockIdx.z);
  int swz = (lin & 7) * 32 + (lin >> 3);
  int bz = swz >> 5;
  int rem = swz & 31;
  int by = rem >> 2, bx = rem & 3;

  const int b = bz;
  const int m0 = by * 256, n0 = bx * 192;
  const unsigned short* Ab = A + (long long)b * 1572864;
  const unsigned short* Bb = B + (long long)b * 589824;

  const int tid = threadIdx.x;
  const int w = tid >> 6, lane = tid & 63;
  const int wr = w >> 2, wn = w & 3;
  const int fr = lane & 15, fq = lane >> 4;

  f32x4 acc[8][3] = {};

  auto stageA = [&](int buf, int kt) {
    #pragma unroll
    for (int s = 0; s < 4; ++s) {
      int g = s * 512 + tid;
      int row = g >> 3, slot = g & 7;
      int sg = (slot - row) & 7;
      const unsigned short* ga = Ab + (long long)(m0 + row) * 768 + kt + sg * 8;
      __builtin_amdgcn_global_load_lds(
          (const __attribute__((address_space(1))) void*)ga,
          (__attribute__((address_space(3))) void*)(&As[buf][0] + g * 16), 16, 0, 0);
    }
  };
  auto stageB = [&](int buf, int kt) {
    #pragma unroll
    for (int s = 0; s < 3; ++s) {
      int g = s * 512 + tid;
      int row = g >> 3, slot = g & 7;
      int sg = (slot - row) & 7;
      const unsigned short* gb = Bb + (long long)(n0 + row) * 768 + kt + sg * 8;
      __builtin_amdgcn_global_load_lds(
          (const __attribute__((address_space(1))) void*)gb,
          (__attribute__((address_space(3))) void*)(&Bs[buf][0] + g * 16), 16, 0, 0);
    }
  };

  stageA(0, 0);
  stageB(0, 0);
  stageA(1, 64);
  asm volatile("s_waitcnt vmcnt(4)" ::: "memory");
  __builtin_amdgcn_s_barrier();

  for (int t = 0; t < 12; ++t) {
    const char* as = &As[t % 3][0];
    const char* bs = &Bs[t & 1][0];

    if (t < 11) stageB((t + 1) & 1, (t + 1) * 64);
    if (t < 10) stageA((t + 2) % 3, (t + 2) * 64);

    #pragma unroll
    for (int kk = 0; kk < 2; ++kk) {
      short8 a[8], bb[3];
      #pragma unroll
      for (int i = 0; i < 8; ++i) {
        int r = wr * 128 + i * 16 + fr;
        a[i] = *reinterpret_cast<const short8*>(as + r * 128 + (((kk * 4 + fq) + r) & 7) * 16);
      }
      #pragma unroll
      for (int j = 0; j < 3; ++j) {
        int r = wn * 48 + j * 16 + fr;
        bb[j] = *reinterpret_cast<const short8*>(bs + r * 128 + (((kk * 4 + fq) + r) & 7) * 16);
      }
      __builtin_amdgcn_s_setprio(1);
      #pragma unroll
      for (int i = 0; i < 8; ++i)
        #pragma unroll
        for (int j = 0; j < 3; ++j)
          acc[i][j] = __builtin_amdgcn_mfma_f32_16x16x32_bf16(a[i], bb[j], acc[i][j], 0, 0, 0);
      __builtin_amdgcn_s_setprio(0);
    }

    if (t < 10)       asm volatile("s_waitcnt vmcnt(4)" ::: "memory");
    else if (t == 10) asm volatile("s_waitcnt vmcnt(0)" ::: "memory");
    __builtin_amdgcn_s_barrier();
  }

  const long long ob = (long long)b * 1572864;
  #pragma unroll
  for (int i = 0; i < 8; ++i)
    #pragma unroll
    for (int j = 0; j < 3; ++j)
      #pragma unroll
      for (int r = 0; r < 4; ++r) {
        int row = m0 + wr * 128 + i * 16 + fq * 4 + r;
        int col = n0 + wn * 48 + j * 16 + fr;
        C[ob + (long long)row * 768 + col] = acc[i][j][r] * SCALE + rowv[b * 768 + col];
      }
}

extern "C" void kernel_launch(void* const* d_in, const int* in_sizes, int n_in,
                              void* d_out, int out_size, void* d_ws, size_t ws_size,
                              hipStream_t stream)
{
  const float* query = (const float*)d_in[0];
  const float* key   = (const float*)d_in[1];
  const float* prev  = (const float*)d_in[3];
  const int*   mask  = (const int*)d_in[4];
  const float* Wq    = (const float*)d_in[5];
  const float* bq    = (const float*)d_in[6];
  const float* Wk    = (const float*)d_in[7];
  const float* bk    = (const float*)d_in[8];
  const float* Wc    = (const float*)d_in[11];
  const float* bc    = (const float*)d_in[12];
  float* out = (float*)d_out;

  char* p = (char*)d_ws;
  size_t off = 0;
  auto alloc = [&](size_t bytes) {
    char* r = p + off;
    off += (bytes + 255) & ~(size_t)255;
    return r;
  };
  unsigned short* query_bf = (unsigned short*)alloc(12582912ull * 2);
  unsigned short* keyzT_bf = (unsigned short*)alloc(4718592ull * 2);
  unsigned short* WqT_bf   = (unsigned short*)alloc(589824ull * 2);
  unsigned short* WkT_bf   = (unsigned short*)alloc(589824ull * 2);
  unsigned short* prev_bf  = (unsigned short*)alloc(589824ull * 2);
  unsigned short* Wc2_bf   = (unsigned short*)alloc(589824ull * 2);
  float*          Mt_f     = (float*)alloc(589824ull * 4);
  unsigned short* Mt_bf    = (unsigned short*)alloc(589824ull * 2);
  unsigned short* W2_bf    = (unsigned short*)alloc(589824ull * 2);
  unsigned short* Tt_bf    = (unsigned short*)alloc(4718592ull * 2);
  unsigned short* Pt_bf    = (unsigned short*)alloc(4718592ull * 2);
  float*          s1f      = (float*)alloc(6144ull * 4);
  float*          sm0f     = (float*)alloc(6144ull * 4);
  float*          uv       = (float*)alloc(768ull * 4);
  float*          w3v      = (float*)alloc(768ull * 4);
  float*          rowv     = (float*)alloc(6144ull * 4);
  (void)ws_size; (void)in_sizes; (void)n_in; (void)out_size;

  // 1) all conversions/transposes
  k_prep_all<<<dim3(12, 12, 34), dim3(256), 0, stream>>>(
      Wq, Wk, key, mask, prev, Wc, query,
      WqT_bf, WkT_bf, keyzT_bf, prev_bf, Wc2_bf, query_bf);
  // 2) G1 + W2
  gemm_g1w2<<<dim3(12, 12, 2), dim3(256), 0, stream>>>(
      Wc2_bf, prev_bf, WqT_bf, WkT_bf, Wc, Mt_f, Mt_bf, W2_bf);
  // 3) u, w3, s1, sm0 (wide launch — latency-bound work needs TLP, r14 lesson)
  k_sums<<<dim3(1920), dim3(256), 0, stream>>>(WqT_bf, WkT_bf, bk, bq, Mt_f, mask,
                                               uv, w3v, s1f, sm0f);
  // 4) G3': Tt[b] = NT(Mt, keyzT[b])
  g34_pipe<3><<<dim3(4, 8, 8), dim3(512), 0, stream>>>(
      Mt_bf, 0ll, keyzT_bf, 589824ll, Tt_bf,
      (const float*)nullptr, (const float*)nullptr);
  // 5) G4': Pt[b] = NT(Tt[b], W2) + s1[b][m]*u[n]
  g34_pipe<4><<<dim3(4, 8, 8), dim3(512), 0, stream>>>(
      Tt_bf, 589824ll, W2_bf, 0ll, Pt_bf, s1f, uv);
  // 6) row constants (wide launch)
  k_row<<<dim3(1536), dim3(256), 0, stream>>>(Tt_bf, w3v, s1f, sm0f, bq, bk, bc, rowv);
  // 7) G5
  g5_pipe<<<dim3(4, 8, 8), dim3(512), 0, stream>>>(query_bf, Pt_bf, out, rowv);
}